// Round 1
// baseline (185.792 us; speedup 1.0000x reference)
//
#include <hip/hip_runtime.h>
#include <cstdint>

typedef unsigned short u16;
typedef unsigned int u32;
typedef float f32x4 __attribute__((ext_vector_type(4)));
typedef __bf16 bf16x8 __attribute__((ext_vector_type(8)));
typedef u16 u16x8 __attribute__((ext_vector_type(8)));

#define B_ 2
#define S_ 2048
#define NX_ 1024
#define NH_ 16
#define HD_ 64
#define T3_ 3072
#define M_ 4096          // B_*S_ tokens
#define SCL 0.18033688011112042f   // 0.125 * log2(e)

__device__ __forceinline__ u16 f2bf(float f) {
    u32 u = __float_as_uint(f);
    u += 0x7FFF + ((u >> 16) & 1);     // RNE
    return (u16)(u >> 16);
}

__device__ __forceinline__ void gload_lds16(const void* g, void* l) {
    auto gp = reinterpret_cast<const __attribute__((address_space(1))) u32*>(
        reinterpret_cast<uintptr_t>(g));
    auto lp = reinterpret_cast<__attribute__((address_space(3))) u32*>(
        reinterpret_cast<uintptr_t>(l));
    __builtin_amdgcn_global_load_lds(gp, lp, 16, 0, 0);
}

// ---------------- convert f32 -> bf16, vectorized ----------------
__global__ __launch_bounds__(256) void cvt_bf16_kernel(const float* __restrict__ X,
                                                       u16* __restrict__ Y) {
    int i = (blockIdx.x * 256 + threadIdx.x) * 4;
    float4 v = *reinterpret_cast<const float4*>(X + i);
    uint2 o;
    o.x = (u32)f2bf(v.x) | ((u32)f2bf(v.y) << 16);
    o.y = (u32)f2bf(v.z) | ((u32)f2bf(v.w) << 16);
    *reinterpret_cast<uint2*>(Y + i) = o;
}

// ---------------- transpose + convert: W[K][N] f32 -> WT[N][K] bf16 ----------------
__global__ __launch_bounds__(256) void transpose_cvt_kernel(const float* __restrict__ W,
                                                            u16* __restrict__ WT,
                                                            int K, int N) {
    __shared__ float tile[32][33];
    int nbx = N >> 5;
    int nb = (blockIdx.x % nbx) << 5;
    int kb = (blockIdx.x / nbx) << 5;
    int tx = threadIdx.x & 31, ty = threadIdx.x >> 5;
#pragma unroll
    for (int i = 0; i < 32; i += 8)
        tile[ty + i][tx] = W[(size_t)(kb + ty + i) * N + nb + tx];
    __syncthreads();
#pragma unroll
    for (int i = 0; i < 32; i += 8)
        WT[(size_t)(nb + ty + i) * K + kb + tx] = f2bf(tile[tx][ty + i]);
}

// ---------------- bf16 GEMM: C[M][N] = A[M][K] * Bt[N][K]^T + bias ----------------
// m97 structure: 128x128 tile, BK=64, 4 waves (2x2), global_load_lds staging.
#define BM 128
#define BN 128
#define BK 64
__global__ __launch_bounds__(256) void gemm_bt_kernel(const u16* __restrict__ A,
                                                      const u16* __restrict__ Bt,
                                                      const float* __restrict__ bias,
                                                      u16* __restrict__ Cb,
                                                      float* __restrict__ Cf,
                                                      int M, int N, int K) {
    __shared__ u16 a_lds[BM * BK];
    __shared__ u16 b_lds[BN * BK];
    int nbn = N / BN;
    int nwg = gridDim.x;
    int orig = blockIdx.x;
    int wg = (orig & 7) * (nwg >> 3) + (orig >> 3);   // XCD-contiguous chunks
    int bm = wg / nbn, bn = wg % nbn;
    int t = threadIdx.x;
    int w = t >> 6, l = t & 63, lg = l >> 4, lr = l & 15;
    int wr = w >> 1, wc = w & 1;
    const u16* Abase = A + (size_t)bm * BM * K;
    const u16* Bbase = Bt + (size_t)bn * BN * K;

    f32x4 zero4 = {0.f, 0.f, 0.f, 0.f};
    f32x4 acc[4][4];
#pragma unroll
    for (int m = 0; m < 4; ++m)
#pragma unroll
        for (int n = 0; n < 4; ++n) acc[m][n] = zero4;

    int nkt = K / BK;
    for (int kt = 0; kt < nkt; ++kt) {
#pragma unroll
        for (int it = 0; it < 4; ++it) {
            int idx = it * 256 + t;          // 16B chunk id
            int row = idx >> 3, ck = idx & 7;
            int ldsoff = (it * 256 + w * 64) * 8;   // wave-uniform, u16 units
            gload_lds16(Abase + (size_t)row * K + kt * BK + ck * 8, a_lds + ldsoff);
            gload_lds16(Bbase + (size_t)row * K + kt * BK + ck * 8, b_lds + ldsoff);
        }
        __syncthreads();
#pragma unroll
        for (int ks = 0; ks < 2; ++ks) {
            bf16x8 af[4], bf[4];
#pragma unroll
            for (int m = 0; m < 4; ++m)
                af[m] = *reinterpret_cast<const bf16x8*>(
                    a_lds + (wr * 64 + m * 16 + lr) * BK + ks * 32 + lg * 8);
#pragma unroll
            for (int n = 0; n < 4; ++n)
                bf[n] = *reinterpret_cast<const bf16x8*>(
                    b_lds + (wc * 64 + n * 16 + lr) * BK + ks * 32 + lg * 8);
#pragma unroll
            for (int m = 0; m < 4; ++m)
#pragma unroll
                for (int n = 0; n < 4; ++n)
                    acc[m][n] = __builtin_amdgcn_mfma_f32_16x16x32_bf16(
                        af[m], bf[n], acc[m][n], 0, 0, 0);
        }
        __syncthreads();
    }
    // epilogue: D row=(lg*4+r), col=lr within each 16x16 fragment
#pragma unroll
    for (int n = 0; n < 4; ++n) {
        int col = bn * BN + wc * 64 + n * 16 + lr;
        float bv = bias[col];
#pragma unroll
        for (int m = 0; m < 4; ++m) {
            int row0 = bm * BM + wr * 64 + m * 16 + lg * 4;
#pragma unroll
            for (int r = 0; r < 4; ++r) {
                float v = acc[m][n][r] + bv;
                if (Cf) Cf[(size_t)(row0 + r) * N + col] = v;
                else    Cb[(size_t)(row0 + r) * N + col] = f2bf(v);
            }
        }
    }
}

// ---------------- flash attention: qkv bf16 [M][3072] -> out bf16 [M][1024] ----------------
// block = 256 thr (4 waves), q-tile 128 (wave owns 32 rows), kv-tile 64, causal.
__global__ __launch_bounds__(256) void attn_kernel(const u16* __restrict__ qkv,
                                                   u16* __restrict__ outa) {
    __shared__ u16 k_lds[64][72];    // K[kidx][d], pad 8 -> 144B rows
    __shared__ u16 vT_lds[64][72];   // V^T[d][kidx]
    __shared__ u16 p_lds[128][72];   // P[q][kidx]

    int bid = blockIdx.x;
    int g = bid & 31;                 // (b,h) group: same bid%8 -> same XCD
    int j = bid >> 5;
    int qt = (j < 8) ? j : (23 - j);  // pair (qt, 15-qt) for causal balance
    int b = g >> 4, h = g & 15;
    int t = threadIdx.x, w = t >> 6, l = t & 63, lg = l >> 4, lr = l & 15;
    int qb = qt * 128;
    const u16* base = qkv + (size_t)b * S_ * T3_;

    // hoist Q fragments to registers: A layout row=lr, k=lg*8+i
    bf16x8 qf[2][2];
#pragma unroll
    for (int m = 0; m < 2; ++m)
#pragma unroll
        for (int ks = 0; ks < 2; ++ks) {
            int row = qb + w * 32 + m * 16 + lr;
            qf[m][ks] = *reinterpret_cast<const bf16x8*>(
                base + (size_t)row * T3_ + h * 64 + ks * 32 + lg * 8);
        }

    f32x4 zero4 = {0.f, 0.f, 0.f, 0.f};
    f32x4 oacc[2][4];
#pragma unroll
    for (int m = 0; m < 2; ++m)
#pragma unroll
        for (int n = 0; n < 4; ++n) oacc[m][n] = zero4;
    float mrun[8], lrun[8];
#pragma unroll
    for (int i = 0; i < 8; ++i) { mrun[i] = -1e30f; lrun[i] = 0.f; }

    int nkt = (qb + 128) >> 6;
    for (int kt = 0; kt < nkt; ++kt) {
        int kb = kt * 64;
        {   // stage K tile (coalesced 16B copies)
            int row = t >> 3, d0 = (t & 7) * 8;
#pragma unroll
            for (int p = 0; p < 2; ++p) {
                const u16* src = base + (size_t)(kb + row + p * 32) * T3_ + NX_ + h * 64 + d0;
                *reinterpret_cast<u16x8*>(&k_lds[row + p * 32][d0]) =
                    *reinterpret_cast<const u16x8*>(src);
            }
        }
        {   // stage V^T (transpose via scalar LDS writes)
            int kidx = t & 31, d0 = (t >> 5) * 8;
#pragma unroll
            for (int p = 0; p < 2; ++p) {
                const u16* src = base + (size_t)(kb + kidx + p * 32) * T3_ + 2 * NX_ + h * 64 + d0;
                u16x8 vv = *reinterpret_cast<const u16x8*>(src);
#pragma unroll
                for (int jj = 0; jj < 8; ++jj)
                    vT_lds[d0 + jj][kidx + p * 32] = vv[jj];
            }
        }
        __syncthreads();

        // S = Q K^T (raw, scale folded into exp)
        f32x4 sacc[2][4];
#pragma unroll
        for (int m = 0; m < 2; ++m)
#pragma unroll
            for (int n = 0; n < 4; ++n) sacc[m][n] = zero4;
#pragma unroll
        for (int ks = 0; ks < 2; ++ks) {
            bf16x8 kf[4];
#pragma unroll
            for (int n = 0; n < 4; ++n)
                kf[n] = *reinterpret_cast<const bf16x8*>(&k_lds[n * 16 + lr][ks * 32 + lg * 8]);
#pragma unroll
            for (int m = 0; m < 2; ++m)
#pragma unroll
                for (int n = 0; n < 4; ++n)
                    sacc[m][n] = __builtin_amdgcn_mfma_f32_16x16x32_bf16(
                        qf[m][ks], kf[n], sacc[m][n], 0, 0, 0);
        }

        // causal mask + wave-parallel online softmax (16-lane column groups)
#pragma unroll
        for (int m = 0; m < 2; ++m) {
#pragma unroll
            for (int r = 0; r < 4; ++r) {
                int qg = qb + w * 32 + m * 16 + lg * 4 + r;
                float mx = -1e30f;
#pragma unroll
                for (int n = 0; n < 4; ++n) {
                    int kg = kb + n * 16 + lr;
                    float s = (kg <= qg) ? sacc[m][n][r] : -1e30f;
                    sacc[m][n][r] = s;
                    mx = fmaxf(mx, s);
                }
#pragma unroll
                for (int off = 1; off < 16; off <<= 1)
                    mx = fmaxf(mx, __shfl_xor(mx, off));
                int i8 = m * 4 + r;
                float mnew = fmaxf(mrun[i8], mx);
                float fsc = exp2f((mrun[i8] - mnew) * SCL);
                mrun[i8] = mnew;
                float rs = 0.f;
#pragma unroll
                for (int n = 0; n < 4; ++n) {
                    float p = exp2f((sacc[m][n][r] - mnew) * SCL);
                    sacc[m][n][r] = p;
                    rs += p;
                }
#pragma unroll
                for (int off = 1; off < 16; off <<= 1)
                    rs += __shfl_xor(rs, off);
                lrun[i8] = lrun[i8] * fsc + rs;
#pragma unroll
                for (int n = 0; n < 4; ++n) oacc[m][n][r] *= fsc;
            }
            // P -> LDS bf16
#pragma unroll
            for (int n = 0; n < 4; ++n)
#pragma unroll
                for (int r = 0; r < 4; ++r)
                    p_lds[w * 32 + m * 16 + lg * 4 + r][n * 16 + lr] = f2bf(sacc[m][n][r]);
        }
        __syncthreads();

        // O += P V
#pragma unroll
        for (int ks = 0; ks < 2; ++ks) {
            bf16x8 pf[2], vf[4];
#pragma unroll
            for (int m = 0; m < 2; ++m)
                pf[m] = *reinterpret_cast<const bf16x8*>(&p_lds[w * 32 + m * 16 + lr][ks * 32 + lg * 8]);
#pragma unroll
            for (int n = 0; n < 4; ++n)
                vf[n] = *reinterpret_cast<const bf16x8*>(&vT_lds[n * 16 + lr][ks * 32 + lg * 8]);
#pragma unroll
            for (int m = 0; m < 2; ++m)
#pragma unroll
                for (int n = 0; n < 4; ++n)
                    oacc[m][n] = __builtin_amdgcn_mfma_f32_16x16x32_bf16(
                        pf[m], vf[n], oacc[m][n], 0, 0, 0);
        }
        __syncthreads();
    }

    // epilogue: O /= l, store bf16 [token][h*64+d]
    u16* ob = outa + (size_t)b * S_ * NX_;
#pragma unroll
    for (int m = 0; m < 2; ++m)
#pragma unroll
        for (int r = 0; r < 4; ++r) {
            float inv = 1.f / lrun[m * 4 + r];
            int row = qb + w * 32 + m * 16 + lg * 4 + r;
#pragma unroll
            for (int n = 0; n < 4; ++n)
                ob[(size_t)row * NX_ + h * 64 + n * 16 + lr] = f2bf(oacc[m][n][r] * inv);
        }
}

extern "C" void kernel_launch(void* const* d_in, const int* in_sizes, int n_in,
                              void* d_out, int out_size, void* d_ws, size_t ws_size,
                              hipStream_t stream) {
    const float* x        = (const float*)d_in[0];
    const float* c_attn_w = (const float*)d_in[1];
    const float* c_attn_b = (const float*)d_in[2];
    const float* c_proj_w = (const float*)d_in[3];
    const float* c_proj_b = (const float*)d_in[4];
    float* out = (float*)d_out;

    u16* xb     = (u16*)d_ws;                         // [4096][1024] bf16  (8 MB)
    u16* wqkvT  = xb + (size_t)M_ * NX_;              // [3072][1024] bf16  (6 MB)
    u16* wprojT = wqkvT + (size_t)T3_ * NX_;          // [1024][1024] bf16  (2 MB)
    u16* qkv    = wprojT + (size_t)NX_ * NX_;         // [4096][3072] bf16  (24 MB)
    u16* attno  = xb;                                 // reuse xb after GEMM1 (8 MB)

    // 1) x -> bf16
    cvt_bf16_kernel<<<(M_ * NX_) / 1024, 256, 0, stream>>>(x, xb);
    // 2) weights -> transposed bf16
    transpose_cvt_kernel<<<(T3_ / 32) * (NX_ / 32), 256, 0, stream>>>(c_attn_w, wqkvT, NX_, T3_);
    transpose_cvt_kernel<<<(NX_ / 32) * (NX_ / 32), 256, 0, stream>>>(c_proj_w, wprojT, NX_, NX_);
    // 3) qkv = x @ c_attn_w + b   (bf16 out)
    gemm_bt_kernel<<<(M_ / BM) * (T3_ / BN), 256, 0, stream>>>(
        xb, wqkvT, c_attn_b, qkv, nullptr, M_, T3_, NX_);
    // 4) attention
    attn_kernel<<<512, 256, 0, stream>>>(qkv, attno);
    // 5) out = attn @ c_proj_w + b  (f32 out)
    gemm_bt_kernel<<<(M_ / BM) * (NX_ / BN), 256, 0, stream>>>(
        attno, wprojT, c_proj_b, nullptr, out, M_, NX_, NX_);
}

// Round 2
// 136.974 us; speedup vs baseline: 1.3564x; 1.3564x over previous
//
#include <hip/hip_runtime.h>
#include <cstdint>

typedef unsigned short u16;
typedef unsigned int u32;
typedef float f32x4 __attribute__((ext_vector_type(4)));
typedef __bf16 bf16x8 __attribute__((ext_vector_type(8)));
typedef u16 u16x8 __attribute__((ext_vector_type(8)));

#define B_ 2
#define S_ 2048
#define NX_ 1024
#define NH_ 16
#define HD_ 64
#define T3_ 3072
#define M_ 4096          // B_*S_ tokens
#define SCL 0.18033688011112042f   // 0.125 * log2(e)

__device__ __forceinline__ u16 f2bf(float f) {
    u32 u = __float_as_uint(f);
    u += 0x7FFF + ((u >> 16) & 1);     // RNE
    return (u16)(u >> 16);
}

__device__ __forceinline__ void gload_lds16(const void* g, void* l) {
    auto gp = reinterpret_cast<const __attribute__((address_space(1))) u32*>(
        reinterpret_cast<uintptr_t>(g));
    auto lp = reinterpret_cast<__attribute__((address_space(3))) u32*>(
        reinterpret_cast<uintptr_t>(l));
    __builtin_amdgcn_global_load_lds(gp, lp, 16, 0, 0);
}

// ---------------- convert f32 -> bf16, vectorized ----------------
__global__ __launch_bounds__(256) void cvt_bf16_kernel(const float* __restrict__ X,
                                                       u16* __restrict__ Y) {
    int i = (blockIdx.x * 256 + threadIdx.x) * 4;
    float4 v = *reinterpret_cast<const float4*>(X + i);
    uint2 o;
    o.x = (u32)f2bf(v.x) | ((u32)f2bf(v.y) << 16);
    o.y = (u32)f2bf(v.z) | ((u32)f2bf(v.w) << 16);
    *reinterpret_cast<uint2*>(Y + i) = o;
}

// ---------------- transpose + convert: W[K][N] f32 -> WT[N][K] bf16 ----------------
__global__ __launch_bounds__(256) void transpose_cvt_kernel(const float* __restrict__ W,
                                                            u16* __restrict__ WT,
                                                            int K, int N) {
    __shared__ float tile[32][33];
    int nbx = N >> 5;
    int nb = (blockIdx.x % nbx) << 5;
    int kb = (blockIdx.x / nbx) << 5;
    int tx = threadIdx.x & 31, ty = threadIdx.x >> 5;
#pragma unroll
    for (int i = 0; i < 32; i += 8)
        tile[ty + i][tx] = W[(size_t)(kb + ty + i) * N + nb + tx];
    __syncthreads();
#pragma unroll
    for (int i = 0; i < 32; i += 8)
        WT[(size_t)(nb + ty + i) * K + kb + tx] = f2bf(tile[tx][ty + i]);
}

// ---------------- bf16 GEMM: C[M][N] = A[M][K] * Bt[N][K]^T + bias ----------------
#define BM 128
#define BN 128
#define BK 64
__global__ __launch_bounds__(256) void gemm_bt_kernel(const u16* __restrict__ A,
                                                      const u16* __restrict__ Bt,
                                                      const float* __restrict__ bias,
                                                      u16* __restrict__ Cb,
                                                      float* __restrict__ Cf,
                                                      int M, int N, int K) {
    __shared__ u16 a_lds[BM * BK];
    __shared__ u16 b_lds[BN * BK];
    int nbn = N / BN;
    int nwg = gridDim.x;
    int orig = blockIdx.x;
    int wg = (orig & 7) * (nwg >> 3) + (orig >> 3);   // XCD-contiguous chunks
    int bm = wg / nbn, bn = wg % nbn;
    int t = threadIdx.x;
    int w = t >> 6, l = t & 63, lg = l >> 4, lr = l & 15;
    int wr = w >> 1, wc = w & 1;
    const u16* Abase = A + (size_t)bm * BM * K;
    const u16* Bbase = Bt + (size_t)bn * BN * K;

    f32x4 zero4 = {0.f, 0.f, 0.f, 0.f};
    f32x4 acc[4][4];
#pragma unroll
    for (int m = 0; m < 4; ++m)
#pragma unroll
        for (int n = 0; n < 4; ++n) acc[m][n] = zero4;

    int nkt = K / BK;
    for (int kt = 0; kt < nkt; ++kt) {
#pragma unroll
        for (int it = 0; it < 4; ++it) {
            int idx = it * 256 + t;          // 16B chunk id
            int row = idx >> 3, ck = idx & 7;
            int ldsoff = (it * 256 + w * 64) * 8;   // wave-uniform, u16 units
            gload_lds16(Abase + (size_t)row * K + kt * BK + ck * 8, a_lds + ldsoff);
            gload_lds16(Bbase + (size_t)row * K + kt * BK + ck * 8, b_lds + ldsoff);
        }
        __syncthreads();
#pragma unroll
        for (int ks = 0; ks < 2; ++ks) {
            bf16x8 af[4], bf[4];
#pragma unroll
            for (int m = 0; m < 4; ++m)
                af[m] = *reinterpret_cast<const bf16x8*>(
                    a_lds + (wr * 64 + m * 16 + lr) * BK + ks * 32 + lg * 8);
#pragma unroll
            for (int n = 0; n < 4; ++n)
                bf[n] = *reinterpret_cast<const bf16x8*>(
                    b_lds + (wc * 64 + n * 16 + lr) * BK + ks * 32 + lg * 8);
#pragma unroll
            for (int m = 0; m < 4; ++m)
#pragma unroll
                for (int n = 0; n < 4; ++n)
                    acc[m][n] = __builtin_amdgcn_mfma_f32_16x16x32_bf16(
                        af[m], bf[n], acc[m][n], 0, 0, 0);
        }
        __syncthreads();
    }
#pragma unroll
    for (int n = 0; n < 4; ++n) {
        int col = bn * BN + wc * 64 + n * 16 + lr;
        float bv = bias[col];
#pragma unroll
        for (int m = 0; m < 4; ++m) {
            int row0 = bm * BM + wr * 64 + m * 16 + lg * 4;
#pragma unroll
            for (int r = 0; r < 4; ++r) {
                float v = acc[m][n][r] + bv;
                if (Cf) Cf[(size_t)(row0 + r) * N + col] = v;
                else    Cb[(size_t)(row0 + r) * N + col] = f2bf(v);
            }
        }
    }
}

// ---------------- Vt: qkv V-part [tok][d] -> Vt[g=b*16+h][d][s] bf16 ----------------
// XOR-swizzled LDS tile so both sides are coalesced & ~conflict-free.
__global__ __launch_bounds__(256) void vt_kernel(const u16* __restrict__ qkv,
                                                 u16* __restrict__ Vt) {
    __shared__ u16 tile[64 * 64];
    int bid = blockIdx.x;
    int g = bid >> 5, sb = (bid & 31) * 64;
    int b = g >> 4, h = g & 15;
    int t = threadIdx.x;
#pragma unroll
    for (int it = 0; it < 2; ++it) {
        int rs = it * 32 + (t >> 3), cd = t & 7;
        u16x8 v = *reinterpret_cast<const u16x8*>(
            qkv + (size_t)(b * S_ + sb + rs) * T3_ + 2 * NX_ + h * 64 + cd * 8);
        int c = cd ^ (rs & 7) ^ ((rs >> 3) & 7);
        *reinterpret_cast<u16x8*>(&tile[rs * 64 + c * 8]) = v;
    }
    __syncthreads();
#pragma unroll
    for (int it = 0; it < 2; ++it) {
        int rd = it * 32 + (t >> 3), s0 = (t & 7) * 8;
        u16x8 o;
#pragma unroll
        for (int j = 0; j < 8; ++j) {
            int s = s0 + j;
            int c = (rd >> 3) ^ (s & 7) ^ ((s >> 3) & 7);
            o[j] = tile[s * 64 + c * 8 + (rd & 7)];
        }
        *reinterpret_cast<u16x8*>(Vt + ((size_t)g * 64 + rd) * S_ + sb + s0) = o;
    }
}

// ---------------- flash attention, swapped-QK^T, in-register softmax ----------------
// q-tile 64 (4 waves x 16 q-rows), kv-tile 64, dbuf K/V staged via global_load_lds
// with pre-swizzled source; P packed through swizzled LDS.
__global__ __launch_bounds__(256) void attn_kernel(const u16* __restrict__ qkv,
                                                   const u16* __restrict__ Vt,
                                                   u16* __restrict__ outa) {
    __shared__ u16 k_lds[2][4096];   // [k 64][d 64], chunk16-swizzled ^ (row&7)
    __shared__ u16 v_lds[2][4096];   // [d 64][k 64], chunk16-swizzled ^ (row&7)
    __shared__ u16 p_lds[4096];      // [q 64][k 64], chunk16-swizzled ^ (row&7)

    int bid = blockIdx.x;
    int g = bid & 31;
    int qt = 31 - (bid >> 5);        // largest q-tile first (causal balance)
    int b = g >> 4, h = g & 15;
    int t = threadIdx.x, w = t >> 6, l = t & 63, lg = l >> 4, lr = l & 15;
    int qb = qt * 64;
    const u16* base = qkv + (size_t)b * S_ * T3_;
    const u16* vbase = Vt + (size_t)g * 64 * S_;
    int qrow = qb + w * 16 + lr;     // this lane's q (column of S^T)
    int prow = w * 16 + lr;          // local P row

    bf16x8 qf[2];
#pragma unroll
    for (int ks = 0; ks < 2; ++ks)
        qf[ks] = *reinterpret_cast<const bf16x8*>(
            base + (size_t)qrow * T3_ + h * 64 + ks * 32 + lg * 8);

    f32x4 zero4 = {0.f, 0.f, 0.f, 0.f};
    f32x4 oacc[4];
#pragma unroll
    for (int dc = 0; dc < 4; ++dc) oacc[dc] = zero4;
    float mrun = -1e30f, lrun = 0.f;
    int nkt = qt + 1;
    int srow = w * 8 + (l >> 3);     // staging row (it adds 32)

    auto stage = [&](int kt2, int bs) {
        int kb2 = kt2 * 64;
#pragma unroll
        for (int it = 0; it < 2; ++it) {
            int row = it * 32 + srow;
            int ckg = (l & 7) ^ (row & 7);       // pre-swizzled global chunk
            gload_lds16(base + (size_t)(kb2 + row) * T3_ + NX_ + h * 64 + ckg * 8,
                        &k_lds[bs][(it * 32 + w * 8) * 64]);
            gload_lds16(vbase + (size_t)row * S_ + kb2 + ckg * 8,
                        &v_lds[bs][(it * 32 + w * 8) * 64]);
        }
    };

    stage(0, 0);
    __syncthreads();

    for (int kt = 0; kt < nkt; ++kt) {
        int cur = kt & 1;
        if (kt + 1 < nkt) stage(kt + 1, cur ^ 1);

        // S^T = K Q^T : lane holds S[k = kn*16+lg*4+r][q = qrow]
        f32x4 sacc[4];
#pragma unroll
        for (int kn = 0; kn < 4; ++kn) sacc[kn] = zero4;
        __builtin_amdgcn_s_setprio(1);
#pragma unroll
        for (int ks = 0; ks < 2; ++ks) {
#pragma unroll
            for (int kn = 0; kn < 4; ++kn) {
                bf16x8 kf = *reinterpret_cast<const bf16x8*>(
                    &k_lds[cur][(kn * 16 + lr) * 64 + (((ks * 4 + lg) ^ (lr & 7)) * 8)]);
                sacc[kn] = __builtin_amdgcn_mfma_f32_16x16x32_bf16(
                    kf, qf[ks], sacc[kn], 0, 0, 0);
            }
        }
        __builtin_amdgcn_s_setprio(0);

        if (kt == qt) {   // diagonal tile: causal mask (k_local > q_local)
            int qloc = w * 16 + lr;
#pragma unroll
            for (int kn = 0; kn < 4; ++kn)
#pragma unroll
                for (int r = 0; r < 4; ++r)
                    if (kn * 16 + lg * 4 + r > qloc) sacc[kn][r] = -1e30f;
        }

        // in-register online softmax (16 in-lane + 2 shfl across lg groups)
        float mx = -1e30f;
#pragma unroll
        for (int kn = 0; kn < 4; ++kn)
#pragma unroll
            for (int r = 0; r < 4; ++r) mx = fmaxf(mx, sacc[kn][r]);
        mx = fmaxf(mx, __shfl_xor(mx, 16));
        mx = fmaxf(mx, __shfl_xor(mx, 32));
        float mnew = fmaxf(mrun, mx);
        float fsc = exp2f((mrun - mnew) * SCL);
        mrun = mnew;
        float rs = 0.f;
#pragma unroll
        for (int kn = 0; kn < 4; ++kn)
#pragma unroll
            for (int r = 0; r < 4; ++r) {
                float p = exp2f((sacc[kn][r] - mnew) * SCL);
                sacc[kn][r] = p;
                rs += p;
            }
        rs += __shfl_xor(rs, 16);
        rs += __shfl_xor(rs, 32);
        lrun = lrun * fsc + rs;

        // P -> LDS, packed 8B writes (4 consecutive k per write), swizzled
#pragma unroll
        for (int kn = 0; kn < 4; ++kn) {
            u32 lo = (u32)f2bf(sacc[kn][0]) | ((u32)f2bf(sacc[kn][1]) << 16);
            u32 hi = (u32)f2bf(sacc[kn][2]) | ((u32)f2bf(sacc[kn][3]) << 16);
            int byteoff = prow * 128 + (((2 * kn + (lg >> 1)) ^ (prow & 7)) * 16) + (lg & 1) * 8;
            uint2 pv; pv.x = lo; pv.y = hi;
            *reinterpret_cast<uint2*>(reinterpret_cast<char*>(p_lds) + byteoff) = pv;
        }

        // rescale O by fsc of its q rows (lg*4+r), pulled from lanes 0-15
        float f0 = __shfl(fsc, lg * 4 + 0);
        float f1 = __shfl(fsc, lg * 4 + 1);
        float f2 = __shfl(fsc, lg * 4 + 2);
        float f3 = __shfl(fsc, lg * 4 + 3);
#pragma unroll
        for (int dc = 0; dc < 4; ++dc) {
            oacc[dc][0] *= f0; oacc[dc][1] *= f1;
            oacc[dc][2] *= f2; oacc[dc][3] *= f3;
        }
        __syncthreads();

        // O += P V  (A = P rows, B = Vt rows)
        __builtin_amdgcn_s_setprio(1);
#pragma unroll
        for (int ks = 0; ks < 2; ++ks) {
            bf16x8 pf = *reinterpret_cast<const bf16x8*>(
                reinterpret_cast<char*>(p_lds) + prow * 128 + (((ks * 4 + lg) ^ (prow & 7)) * 16));
#pragma unroll
            for (int dc = 0; dc < 4; ++dc) {
                bf16x8 vf = *reinterpret_cast<const bf16x8*>(
                    &v_lds[cur][(dc * 16 + lr) * 64 + (((ks * 4 + lg) ^ (lr & 7)) * 8)]);
                oacc[dc] = __builtin_amdgcn_mfma_f32_16x16x32_bf16(
                    pf, vf, oacc[dc], 0, 0, 0);
            }
        }
        __builtin_amdgcn_s_setprio(0);
        __syncthreads();
    }

    // epilogue: O /= l ; store bf16 [token][h*64+d]
    float inv = 1.f / lrun;
    float i0 = __shfl(inv, lg * 4 + 0);
    float i1 = __shfl(inv, lg * 4 + 1);
    float i2 = __shfl(inv, lg * 4 + 2);
    float i3 = __shfl(inv, lg * 4 + 3);
    u16* ob = outa + (size_t)b * S_ * NX_;
#pragma unroll
    for (int r = 0; r < 4; ++r) {
        float ir = (r == 0) ? i0 : (r == 1) ? i1 : (r == 2) ? i2 : i3;
        int row = qb + w * 16 + lg * 4 + r;
#pragma unroll
        for (int dc = 0; dc < 4; ++dc)
            ob[(size_t)row * NX_ + h * 64 + dc * 16 + lr] = f2bf(oacc[dc][r] * ir);
    }
}

extern "C" void kernel_launch(void* const* d_in, const int* in_sizes, int n_in,
                              void* d_out, int out_size, void* d_ws, size_t ws_size,
                              hipStream_t stream) {
    const float* x        = (const float*)d_in[0];
    const float* c_attn_w = (const float*)d_in[1];
    const float* c_attn_b = (const float*)d_in[2];
    const float* c_proj_w = (const float*)d_in[3];
    const float* c_proj_b = (const float*)d_in[4];
    float* out = (float*)d_out;

    u16* xb     = (u16*)d_ws;                         // [4096][1024] bf16  (8 MB)
    u16* wqkvT  = xb + (size_t)M_ * NX_;              // [3072][1024] bf16  (6 MB)
    u16* wprojT = wqkvT + (size_t)T3_ * NX_;          // [1024][1024] bf16  (2 MB)
    u16* qkv    = wprojT + (size_t)NX_ * NX_;         // [4096][3072] bf16  (24 MB)
    u16* attno  = xb;                                 // reuse xb after GEMM1 (8 MB)
    u16* Vtp    = (u16*)d_out;                        // scratch: Vt 8 MB inside 16 MB out;
                                                      // fully overwritten by GEMM2 at the end

    // 1) x -> bf16
    cvt_bf16_kernel<<<(M_ * NX_) / 1024, 256, 0, stream>>>(x, xb);
    // 2) weights -> transposed bf16
    transpose_cvt_kernel<<<(T3_ / 32) * (NX_ / 32), 256, 0, stream>>>(c_attn_w, wqkvT, NX_, T3_);
    transpose_cvt_kernel<<<(NX_ / 32) * (NX_ / 32), 256, 0, stream>>>(c_proj_w, wprojT, NX_, NX_);
    // 3) qkv = x @ c_attn_w + b   (bf16 out)
    gemm_bt_kernel<<<(M_ / BM) * (T3_ / BN), 256, 0, stream>>>(
        xb, wqkvT, c_attn_b, qkv, nullptr, M_, T3_, NX_);
    // 4a) V^T per (b,h)
    vt_kernel<<<1024, 256, 0, stream>>>(qkv, Vtp);
    // 4b) attention
    attn_kernel<<<1024, 256, 0, stream>>>(qkv, Vtp, attno);
    // 5) out = attn @ c_proj_w + b  (f32 out)
    gemm_bt_kernel<<<(M_ / BM) * (NX_ / BN), 256, 0, stream>>>(
        attno, wprojT, c_proj_b, nullptr, out, M_, NX_, NX_);
}

// Round 3
// 136.524 us; speedup vs baseline: 1.3609x; 1.0033x over previous
//
#include <hip/hip_runtime.h>
#include <cstdint>

typedef unsigned short u16;
typedef unsigned int u32;
typedef float f32x4 __attribute__((ext_vector_type(4)));
typedef __bf16 bf16x8 __attribute__((ext_vector_type(8)));
typedef __bf16 bf16x4 __attribute__((ext_vector_type(4)));
typedef u16 u16x8 __attribute__((ext_vector_type(8)));

#define B_ 2
#define S_ 2048
#define NX_ 1024
#define NH_ 16
#define HD_ 64
#define T3_ 3072
#define M_ 4096          // B_*S_ tokens
#define SCL 0.18033688011112042f   // 0.125 * log2(e)

__device__ __forceinline__ u16 bfbits(float f) {
    __bf16 h = (__bf16)f;            // native cvt (RNE), 1 op, pairs to v_cvt_pk_bf16_f32
    return __builtin_bit_cast(u16, h);
}

__device__ __forceinline__ void gload_lds16(const void* g, void* l) {
    auto gp = reinterpret_cast<const __attribute__((address_space(1))) u32*>(
        reinterpret_cast<uintptr_t>(g));
    auto lp = reinterpret_cast<__attribute__((address_space(3))) u32*>(
        reinterpret_cast<uintptr_t>(l));
    __builtin_amdgcn_global_load_lds(gp, lp, 16, 0, 0);
}

// ---------------- convert f32 -> bf16, vectorized ----------------
__global__ __launch_bounds__(256) void cvt_bf16_kernel(const float* __restrict__ X,
                                                       u16* __restrict__ Y) {
    int i = (blockIdx.x * 256 + threadIdx.x) * 4;
    float4 v = *reinterpret_cast<const float4*>(X + i);
    bf16x4 o;
    o[0] = (__bf16)v.x; o[1] = (__bf16)v.y; o[2] = (__bf16)v.z; o[3] = (__bf16)v.w;
    *reinterpret_cast<bf16x4*>(Y + i) = o;
}

// ---------------- transpose + convert: W[K][N] f32 -> WT[N][K] bf16 ----------------
__global__ __launch_bounds__(256) void transpose_cvt_kernel(const float* __restrict__ W,
                                                            u16* __restrict__ WT,
                                                            int K, int N) {
    __shared__ float tile[32][33];
    int nbx = N >> 5;
    int nb = (blockIdx.x % nbx) << 5;
    int kb = (blockIdx.x / nbx) << 5;
    int tx = threadIdx.x & 31, ty = threadIdx.x >> 5;
#pragma unroll
    for (int i = 0; i < 32; i += 8)
        tile[ty + i][tx] = W[(size_t)(kb + ty + i) * N + nb + tx];
    __syncthreads();
#pragma unroll
    for (int i = 0; i < 32; i += 8)
        WT[(size_t)(nb + ty + i) * K + kb + tx] = bfbits(tile[tx][ty + i]);
}

// ---------------- bf16 GEMM: C[M][N] = A[M][K] * Bt[N][K]^T + bias ----------------
// If Vt!=null, columns >= vcol0 are written transposed per-head: Vt[g=b*16+h][d][s].
#define BM 128
#define BN 128
#define BK 64
__global__ __launch_bounds__(256) void gemm_bt_kernel(const u16* __restrict__ A,
                                                      const u16* __restrict__ Bt,
                                                      const float* __restrict__ bias,
                                                      u16* __restrict__ Cb,
                                                      float* __restrict__ Cf,
                                                      u16* __restrict__ Vt,
                                                      int vcol0,
                                                      int M, int N, int K) {
    __shared__ u16 a_lds[BM * BK];
    __shared__ u16 b_lds[BN * BK];
    int nbn = N / BN;
    int nwg = gridDim.x;
    int orig = blockIdx.x;
    int wg = (orig & 7) * (nwg >> 3) + (orig >> 3);   // XCD-contiguous chunks
    int bm = wg / nbn, bn = wg % nbn;
    int t = threadIdx.x;
    int w = t >> 6, l = t & 63, lg = l >> 4, lr = l & 15;
    int wr = w >> 1, wc = w & 1;
    const u16* Abase = A + (size_t)bm * BM * K;
    const u16* Bbase = Bt + (size_t)bn * BN * K;

    f32x4 zero4 = {0.f, 0.f, 0.f, 0.f};
    f32x4 acc[4][4];
#pragma unroll
    for (int m = 0; m < 4; ++m)
#pragma unroll
        for (int n = 0; n < 4; ++n) acc[m][n] = zero4;

    int nkt = K / BK;
    for (int kt = 0; kt < nkt; ++kt) {
#pragma unroll
        for (int it = 0; it < 4; ++it) {
            int idx = it * 256 + t;          // 16B chunk id
            int row = idx >> 3, ck = idx & 7;
            int ldsoff = (it * 256 + w * 64) * 8;   // wave-uniform, u16 units
            gload_lds16(Abase + (size_t)row * K + kt * BK + ck * 8, a_lds + ldsoff);
            gload_lds16(Bbase + (size_t)row * K + kt * BK + ck * 8, b_lds + ldsoff);
        }
        __syncthreads();
#pragma unroll
        for (int ks = 0; ks < 2; ++ks) {
            bf16x8 af[4], bf[4];
#pragma unroll
            for (int m = 0; m < 4; ++m)
                af[m] = *reinterpret_cast<const bf16x8*>(
                    a_lds + (wr * 64 + m * 16 + lr) * BK + ks * 32 + lg * 8);
#pragma unroll
            for (int n = 0; n < 4; ++n)
                bf[n] = *reinterpret_cast<const bf16x8*>(
                    b_lds + (wc * 64 + n * 16 + lr) * BK + ks * 32 + lg * 8);
#pragma unroll
            for (int m = 0; m < 4; ++m)
#pragma unroll
                for (int n = 0; n < 4; ++n)
                    acc[m][n] = __builtin_amdgcn_mfma_f32_16x16x32_bf16(
                        af[m], bf[n], acc[m][n], 0, 0, 0);
        }
        __syncthreads();
    }
#pragma unroll
    for (int n = 0; n < 4; ++n) {
        int col0 = bn * BN + wc * 64 + n * 16;
        int col = col0 + lr;
        float bv = bias[col];
        bool isv = (Vt != nullptr) && (col0 >= vcol0);
#pragma unroll
        for (int m = 0; m < 4; ++m) {
            int row0 = bm * BM + wr * 64 + m * 16 + lg * 4;
            if (isv) {
                int nv = col - vcol0, hh = nv >> 6, dd = nv & 63;
                int bb = row0 >> 11, ss = row0 & 2047;
                bf16x4 pk;
#pragma unroll
                for (int r = 0; r < 4; ++r) pk[r] = (__bf16)(acc[m][n][r] + bv);
                *reinterpret_cast<bf16x4*>(
                    Vt + (((size_t)(bb * 16 + hh) * 64 + dd) << 11) + ss) = pk;
            } else {
#pragma unroll
                for (int r = 0; r < 4; ++r) {
                    float v = acc[m][n][r] + bv;
                    if (Cf) Cf[(size_t)(row0 + r) * N + col] = v;
                    else    Cb[(size_t)(row0 + r) * N + col] = bfbits(v);
                }
            }
        }
    }
}

// ---------------- flash attention, swapped-QK^T, in-register softmax ----------------
// Pair-blocks: block handles q-tiles (31-p) then p -> uniform 33 kv-tiles/block.
// q-tile 64 (4 waves x 16 q-rows), kv-tile 64, dbuf K/V via global_load_lds
// with pre-swizzled source; P packed through swizzled LDS; defer-max rescale.
__global__ __launch_bounds__(256) void attn_kernel(const u16* __restrict__ qkv,
                                                   const u16* __restrict__ Vt,
                                                   u16* __restrict__ outa) {
    __shared__ u16 k_lds[2][4096];   // [k 64][d 64], chunk16-swizzled ^ (row&7)
    __shared__ u16 v_lds[2][4096];   // [d 64][k 64], chunk16-swizzled ^ (row&7)
    __shared__ u16 p_lds[4096];      // [q 64][k 64], chunk16-swizzled ^ (row&7)

    int bid = blockIdx.x;
    int g = bid & 31;                // same g -> same XCD (stride 32 ≡ 0 mod 8)
    int pp = bid >> 5;               // pair id 0..15
    int b = g >> 4, h = g & 15;
    int t = threadIdx.x, w = t >> 6, l = t & 63, lg = l >> 4, lr = l & 15;
    const u16* base = qkv + (size_t)b * S_ * T3_;
    const u16* vbase = Vt + (size_t)g * 64 * S_;
    int prow = w * 16 + lr;          // local P row
    int srow = w * 8 + (l >> 3);     // staging row (it adds 32)

    auto stage = [&](int kt2, int bs) {
        int kb2 = kt2 * 64;
#pragma unroll
        for (int it = 0; it < 2; ++it) {
            int row = it * 32 + srow;
            int ckg = (l & 7) ^ (row & 7);       // pre-swizzled global chunk
            gload_lds16(base + (size_t)(kb2 + row) * T3_ + NX_ + h * 64 + ckg * 8,
                        &k_lds[bs][(it * 32 + w * 8) * 64]);
            gload_lds16(vbase + (size_t)row * S_ + kb2 + ckg * 8,
                        &v_lds[bs][(it * 32 + w * 8) * 64]);
        }
    };

    f32x4 zero4 = {0.f, 0.f, 0.f, 0.f};

    for (int pass = 0; pass < 2; ++pass) {
        int qt = pass ? pp : (31 - pp);
        int qb = qt * 64;
        int qrow = qb + w * 16 + lr;     // this lane's q (column of S^T)

        bf16x8 qf[2];
#pragma unroll
        for (int ks = 0; ks < 2; ++ks)
            qf[ks] = *reinterpret_cast<const bf16x8*>(
                base + (size_t)qrow * T3_ + h * 64 + ks * 32 + lg * 8);

        f32x4 oacc[4];
#pragma unroll
        for (int dc = 0; dc < 4; ++dc) oacc[dc] = zero4;
        float mrun = -1e30f, lrun = 0.f;
        int nkt = qt + 1;

        stage(0, 0);
        __syncthreads();

        for (int kt = 0; kt < nkt; ++kt) {
            int cur = kt & 1;
            if (kt + 1 < nkt) stage(kt + 1, cur ^ 1);

            // S^T = K Q^T : lane holds S[k = kn*16+lg*4+r][q = qrow]
            f32x4 sacc[4];
#pragma unroll
            for (int kn = 0; kn < 4; ++kn) sacc[kn] = zero4;
            __builtin_amdgcn_s_setprio(1);
#pragma unroll
            for (int ks = 0; ks < 2; ++ks) {
#pragma unroll
                for (int kn = 0; kn < 4; ++kn) {
                    bf16x8 kf = *reinterpret_cast<const bf16x8*>(
                        &k_lds[cur][(kn * 16 + lr) * 64 + (((ks * 4 + lg) ^ (lr & 7)) * 8)]);
                    sacc[kn] = __builtin_amdgcn_mfma_f32_16x16x32_bf16(
                        kf, qf[ks], sacc[kn], 0, 0, 0);
                }
            }
            __builtin_amdgcn_s_setprio(0);

            if (kt == qt) {   // diagonal tile: causal mask (k_local > q_local)
                int qloc = w * 16 + lr;
#pragma unroll
                for (int kn = 0; kn < 4; ++kn)
#pragma unroll
                    for (int r = 0; r < 4; ++r)
                        if (kn * 16 + lg * 4 + r > qloc) sacc[kn][r] = -1e30f;
            }

            // in-register online softmax (16 in-lane + 2 shfl across lg groups)
            float mx = -1e30f;
#pragma unroll
            for (int kn = 0; kn < 4; ++kn) {
                float a0 = fmaxf(sacc[kn][0], sacc[kn][1]);
                float a1 = fmaxf(sacc[kn][2], sacc[kn][3]);
                mx = fmaxf(mx, fmaxf(a0, a1));
            }
            mx = fmaxf(mx, __shfl_xor(mx, 16));
            mx = fmaxf(mx, __shfl_xor(mx, 32));

            bool noresc = __all(mx <= mrun + 8.0f);   // defer-max: P bounded by 2^(8*SCL)=2.7
            float mnew = noresc ? mrun : fmaxf(mrun, mx);

            float rs = 0.f;
#pragma unroll
            for (int kn = 0; kn < 4; ++kn)
#pragma unroll
                for (int r = 0; r < 4; ++r) {
                    float pv = exp2f((sacc[kn][r] - mnew) * SCL);
                    sacc[kn][r] = pv;
                    rs += pv;
                }
            rs += __shfl_xor(rs, 16);
            rs += __shfl_xor(rs, 32);

            if (noresc) {
                lrun += rs;
            } else {
                float fsc = exp2f((mrun - mnew) * SCL);
                mrun = mnew;
                lrun = lrun * fsc + rs;
                float f0 = __shfl(fsc, lg * 4 + 0);
                float f1 = __shfl(fsc, lg * 4 + 1);
                float f2 = __shfl(fsc, lg * 4 + 2);
                float f3 = __shfl(fsc, lg * 4 + 3);
#pragma unroll
                for (int dc = 0; dc < 4; ++dc) {
                    oacc[dc][0] *= f0; oacc[dc][1] *= f1;
                    oacc[dc][2] *= f2; oacc[dc][3] *= f3;
                }
            }

            // P -> LDS, packed 8B writes (4 consecutive k per write), swizzled
#pragma unroll
            for (int kn = 0; kn < 4; ++kn) {
                bf16x4 pb;
                pb[0] = (__bf16)sacc[kn][0]; pb[1] = (__bf16)sacc[kn][1];
                pb[2] = (__bf16)sacc[kn][2]; pb[3] = (__bf16)sacc[kn][3];
                int byteoff = prow * 128 + (((2 * kn + (lg >> 1)) ^ (prow & 7)) * 16) + (lg & 1) * 8;
                *reinterpret_cast<bf16x4*>(reinterpret_cast<char*>(p_lds) + byteoff) = pb;
            }
            __syncthreads();

            // O += P V  (A = P rows, B = Vt rows)
            __builtin_amdgcn_s_setprio(1);
#pragma unroll
            for (int ks = 0; ks < 2; ++ks) {
                bf16x8 pf = *reinterpret_cast<const bf16x8*>(
                    reinterpret_cast<char*>(p_lds) + prow * 128 + (((ks * 4 + lg) ^ (prow & 7)) * 16));
#pragma unroll
                for (int dc = 0; dc < 4; ++dc) {
                    bf16x8 vf = *reinterpret_cast<const bf16x8*>(
                        &v_lds[cur][(dc * 16 + lr) * 64 + (((ks * 4 + lg) ^ (lr & 7)) * 8)]);
                    oacc[dc] = __builtin_amdgcn_mfma_f32_16x16x32_bf16(
                        pf, vf, oacc[dc], 0, 0, 0);
                }
            }
            __builtin_amdgcn_s_setprio(0);
            __syncthreads();
        }

        // epilogue: O /= l ; store bf16 [token][h*64+d]
        float inv = 1.f / lrun;
        float i0 = __shfl(inv, lg * 4 + 0);
        float i1 = __shfl(inv, lg * 4 + 1);
        float i2 = __shfl(inv, lg * 4 + 2);
        float i3 = __shfl(inv, lg * 4 + 3);
        u16* ob = outa + (size_t)b * S_ * NX_;
#pragma unroll
        for (int r = 0; r < 4; ++r) {
            float ir = (r == 0) ? i0 : (r == 1) ? i1 : (r == 2) ? i2 : i3;
            int row = qb + w * 16 + lg * 4 + r;
#pragma unroll
            for (int dc = 0; dc < 4; ++dc)
                ob[(size_t)row * NX_ + h * 64 + dc * 16 + lr] = bfbits(oacc[dc][r] * ir);
        }
    }
}

extern "C" void kernel_launch(void* const* d_in, const int* in_sizes, int n_in,
                              void* d_out, int out_size, void* d_ws, size_t ws_size,
                              hipStream_t stream) {
    const float* x        = (const float*)d_in[0];
    const float* c_attn_w = (const float*)d_in[1];
    const float* c_attn_b = (const float*)d_in[2];
    const float* c_proj_w = (const float*)d_in[3];
    const float* c_proj_b = (const float*)d_in[4];
    float* out = (float*)d_out;

    u16* xb     = (u16*)d_ws;                         // [4096][1024] bf16  (8 MB)
    u16* wqkvT  = xb + (size_t)M_ * NX_;              // [3072][1024] bf16  (6 MB)
    u16* wprojT = wqkvT + (size_t)T3_ * NX_;          // [1024][1024] bf16  (2 MB)
    u16* qkv    = wprojT + (size_t)NX_ * NX_;         // [4096][3072] bf16  (24 MB; V part unused)
    u16* attno  = xb;                                 // reuse xb after GEMM1 (8 MB)
    u16* Vtp    = (u16*)d_out;                        // scratch: Vt 8 MB inside 16 MB out;
                                                      // fully overwritten by GEMM2 at the end

    // 1) x -> bf16
    cvt_bf16_kernel<<<(M_ * NX_) / 1024, 256, 0, stream>>>(x, xb);
    // 2) weights -> transposed bf16
    transpose_cvt_kernel<<<(T3_ / 32) * (NX_ / 32), 256, 0, stream>>>(c_attn_w, wqkvT, NX_, T3_);
    transpose_cvt_kernel<<<(NX_ / 32) * (NX_ / 32), 256, 0, stream>>>(c_proj_w, wprojT, NX_, NX_);
    // 3) qkv = x @ c_attn_w + b (bf16 out); V-part written transposed to Vtp
    gemm_bt_kernel<<<(M_ / BM) * (T3_ / BN), 256, 0, stream>>>(
        xb, wqkvT, c_attn_b, qkv, nullptr, Vtp, 2 * NX_, M_, T3_, NX_);
    // 4) attention (pair-balanced)
    attn_kernel<<<512, 256, 0, stream>>>(qkv, Vtp, attno);
    // 5) out = attn @ c_proj_w + b  (f32 out)
    gemm_bt_kernel<<<(M_ / BM) * (NX_ / BN), 256, 0, stream>>>(
        attno, wprojT, c_proj_b, nullptr, out, nullptr, 0, M_, NX_, NX_);
}

// Round 4
// 127.900 us; speedup vs baseline: 1.4526x; 1.0674x over previous
//
#include <hip/hip_runtime.h>
#include <cstdint>

typedef unsigned short u16;
typedef unsigned int u32;
typedef float f32x4 __attribute__((ext_vector_type(4)));
typedef __bf16 bf16x8 __attribute__((ext_vector_type(8)));
typedef __bf16 bf16x4 __attribute__((ext_vector_type(4)));
typedef u16 u16x8 __attribute__((ext_vector_type(8)));

#define B_ 2
#define S_ 2048
#define NX_ 1024
#define NH_ 16
#define HD_ 64
#define T3_ 3072
#define M_ 4096          // B_*S_ tokens
#define SCL 0.18033688011112042f   // 0.125 * log2(e)

__device__ __forceinline__ u16 bfbits(float f) {
    __bf16 h = (__bf16)f;            // native cvt (RNE), pairs to v_cvt_pk_bf16_f32
    return __builtin_bit_cast(u16, h);
}

__device__ __forceinline__ void gload_lds16(const void* g, void* l) {
    auto gp = reinterpret_cast<const __attribute__((address_space(1))) u32*>(
        reinterpret_cast<uintptr_t>(g));
    auto lp = reinterpret_cast<__attribute__((address_space(3))) u32*>(
        reinterpret_cast<uintptr_t>(l));
    __builtin_amdgcn_global_load_lds(gp, lp, 16, 0, 0);
}

// ---------------- convert f32 -> bf16, vectorized ----------------
__global__ __launch_bounds__(256) void cvt_bf16_kernel(const float* __restrict__ X,
                                                       u16* __restrict__ Y) {
    int i = (blockIdx.x * 256 + threadIdx.x) * 4;
    float4 v = *reinterpret_cast<const float4*>(X + i);
    bf16x4 o;
    o[0] = (__bf16)v.x; o[1] = (__bf16)v.y; o[2] = (__bf16)v.z; o[3] = (__bf16)v.w;
    *reinterpret_cast<bf16x4*>(Y + i) = o;
}

// ---------------- transpose + convert: W[K][N] f32 -> WT[N][K] bf16 ----------------
__global__ __launch_bounds__(256) void transpose_cvt_kernel(const float* __restrict__ W,
                                                            u16* __restrict__ WT,
                                                            int K, int N) {
    __shared__ float tile[32][33];
    int nbx = N >> 5;
    int nb = (blockIdx.x % nbx) << 5;
    int kb = (blockIdx.x / nbx) << 5;
    int tx = threadIdx.x & 31, ty = threadIdx.x >> 5;
#pragma unroll
    for (int i = 0; i < 32; i += 8)
        tile[ty + i][tx] = W[(size_t)(kb + ty + i) * N + nb + tx];
    __syncthreads();
#pragma unroll
    for (int i = 0; i < 32; i += 8)
        WT[(size_t)(nb + ty + i) * K + kb + tx] = bfbits(tile[tx][ty + i]);
}

// ---------------- bf16 GEMM: C[M][N] = A[M][K] * Bt[N][K]^T + bias ----------------
// If Vt!=null, columns >= vcol0 are written transposed per-head: Vt[g=b*16+h][d][s].
#define BM 128
#define BN 128
#define BK 64
__global__ __launch_bounds__(256) void gemm_bt_kernel(const u16* __restrict__ A,
                                                      const u16* __restrict__ Bt,
                                                      const float* __restrict__ bias,
                                                      u16* __restrict__ Cb,
                                                      float* __restrict__ Cf,
                                                      u16* __restrict__ Vt,
                                                      int vcol0,
                                                      int M, int N, int K) {
    __shared__ u16 a_lds[BM * BK];
    __shared__ u16 b_lds[BN * BK];
    int nbn = N / BN;
    int nwg = gridDim.x;
    int orig = blockIdx.x;
    int wg = (orig & 7) * (nwg >> 3) + (orig >> 3);   // XCD-contiguous chunks
    int bm = wg / nbn, bn = wg % nbn;
    int t = threadIdx.x;
    int w = t >> 6, l = t & 63, lg = l >> 4, lr = l & 15;
    int wr = w >> 1, wc = w & 1;
    const u16* Abase = A + (size_t)bm * BM * K;
    const u16* Bbase = Bt + (size_t)bn * BN * K;

    f32x4 zero4 = {0.f, 0.f, 0.f, 0.f};
    f32x4 acc[4][4];
#pragma unroll
    for (int m = 0; m < 4; ++m)
#pragma unroll
        for (int n = 0; n < 4; ++n) acc[m][n] = zero4;

    int nkt = K / BK;
    for (int kt = 0; kt < nkt; ++kt) {
#pragma unroll
        for (int it = 0; it < 4; ++it) {
            int idx = it * 256 + t;          // 16B chunk id
            int row = idx >> 3, ck = idx & 7;
            int ldsoff = (it * 256 + w * 64) * 8;   // wave-uniform, u16 units
            gload_lds16(Abase + (size_t)row * K + kt * BK + ck * 8, a_lds + ldsoff);
            gload_lds16(Bbase + (size_t)row * K + kt * BK + ck * 8, b_lds + ldsoff);
        }
        __syncthreads();
#pragma unroll
        for (int ks = 0; ks < 2; ++ks) {
            bf16x8 af[4], bf[4];
#pragma unroll
            for (int m = 0; m < 4; ++m)
                af[m] = *reinterpret_cast<const bf16x8*>(
                    a_lds + (wr * 64 + m * 16 + lr) * BK + ks * 32 + lg * 8);
#pragma unroll
            for (int n = 0; n < 4; ++n)
                bf[n] = *reinterpret_cast<const bf16x8*>(
                    b_lds + (wc * 64 + n * 16 + lr) * BK + ks * 32 + lg * 8);
#pragma unroll
            for (int m = 0; m < 4; ++m)
#pragma unroll
                for (int n = 0; n < 4; ++n)
                    acc[m][n] = __builtin_amdgcn_mfma_f32_16x16x32_bf16(
                        af[m], bf[n], acc[m][n], 0, 0, 0);
        }
        __syncthreads();
    }
#pragma unroll
    for (int n = 0; n < 4; ++n) {
        int col0 = bn * BN + wc * 64 + n * 16;
        int col = col0 + lr;
        float bv = bias[col];
        bool isv = (Vt != nullptr) && (col0 >= vcol0);
#pragma unroll
        for (int m = 0; m < 4; ++m) {
            int row0 = bm * BM + wr * 64 + m * 16 + lg * 4;
            if (isv) {
                int nv = col - vcol0, hh = nv >> 6, dd = nv & 63;
                int bb = row0 >> 11, ss = row0 & 2047;
                bf16x4 pk;
#pragma unroll
                for (int r = 0; r < 4; ++r) pk[r] = (__bf16)(acc[m][n][r] + bv);
                *reinterpret_cast<bf16x4*>(
                    Vt + (((size_t)(bb * 16 + hh) * 64 + dd) << 11) + ss) = pk;
            } else {
#pragma unroll
                for (int r = 0; r < 4; ++r) {
                    float v = acc[m][n][r] + bv;
                    if (Cf) Cf[(size_t)(row0 + r) * N + col] = v;
                    else    Cb[(size_t)(row0 + r) * N + col] = bfbits(v);
                }
            }
        }
    }
}

// ---------------- flash attention, swapped-QK^T, in-register softmax ----------------
// One q-tile (64 rows) per block, 1024 blocks. qt chosen so each CU's 4 blocks
// (mod-256 round-robin dispatch) sum to a uniform 66 kv-tile-iters:
// qt in {j0, 31-j0, 8+j0, 23-j0}. Single barrier per kv-tile (P is wave-private).
__global__ __launch_bounds__(256) void attn_kernel(const u16* __restrict__ qkv,
                                                   const u16* __restrict__ Vt,
                                                   u16* __restrict__ outa) {
    __shared__ u16 k_lds[2][4096];   // [k 64][d 64], chunk16-swizzled ^ (row&7)
    __shared__ u16 v_lds[2][4096];   // [d 64][k 64], chunk16-swizzled ^ (row&7)
    __shared__ u16 p_lds[4096];      // [q 64][k 64], chunk16-swizzled ^ (row&7)

    int bid = blockIdx.x;
    int g = bid & 31;                // same g -> same XCD (stride 32 ≡ 0 mod 8)
    int j = bid >> 5;                // 0..31
    int j0 = j & 7, kk = j >> 3;
    int qt = (kk == 0) ? j0 : (kk == 1) ? (31 - j0) : (kk == 2) ? (8 + j0) : (23 - j0);
    int b = g >> 4, h = g & 15;
    int t = threadIdx.x, w = t >> 6, l = t & 63, lg = l >> 4, lr = l & 15;
    const u16* base = qkv + (size_t)b * S_ * T3_;
    const u16* vbase = Vt + (size_t)g * 64 * S_;
    int prow = w * 16 + lr;          // local P row (wave-private slab)
    int srow = w * 8 + (l >> 3);     // staging row (it adds 32)
    int qb = qt * 64;
    int qrow = qb + w * 16 + lr;     // this lane's q (column of S^T)

    auto stage = [&](int kt2, int bs) {
        int kb2 = kt2 * 64;
#pragma unroll
        for (int it = 0; it < 2; ++it) {
            int row = it * 32 + srow;
            int ckg = (l & 7) ^ (row & 7);       // pre-swizzled global chunk
            gload_lds16(base + (size_t)(kb2 + row) * T3_ + NX_ + h * 64 + ckg * 8,
                        &k_lds[bs][(it * 32 + w * 8) * 64]);
            gload_lds16(vbase + (size_t)row * S_ + kb2 + ckg * 8,
                        &v_lds[bs][(it * 32 + w * 8) * 64]);
        }
    };

    f32x4 zero4 = {0.f, 0.f, 0.f, 0.f};

    bf16x8 qf[2];
#pragma unroll
    for (int ks = 0; ks < 2; ++ks)
        qf[ks] = *reinterpret_cast<const bf16x8*>(
            base + (size_t)qrow * T3_ + h * 64 + ks * 32 + lg * 8);

    f32x4 oacc[4];
#pragma unroll
    for (int dc = 0; dc < 4; ++dc) oacc[dc] = zero4;
    float mrun = -1e30f, lrun = 0.f;
    int nkt = qt + 1;

    stage(0, 0);
    __syncthreads();

    for (int kt = 0; kt < nkt; ++kt) {
        int cur = kt & 1;
        if (kt + 1 < nkt) stage(kt + 1, cur ^ 1);   // issue early; drains at end barrier

        // S^T = K Q^T : lane holds S[k = kn*16+lg*4+r][q = qrow]
        f32x4 sacc[4];
#pragma unroll
        for (int kn = 0; kn < 4; ++kn) sacc[kn] = zero4;
        __builtin_amdgcn_s_setprio(1);
#pragma unroll
        for (int ks = 0; ks < 2; ++ks) {
#pragma unroll
            for (int kn = 0; kn < 4; ++kn) {
                bf16x8 kf = *reinterpret_cast<const bf16x8*>(
                    &k_lds[cur][(kn * 16 + lr) * 64 + (((ks * 4 + lg) ^ (lr & 7)) * 8)]);
                sacc[kn] = __builtin_amdgcn_mfma_f32_16x16x32_bf16(
                    kf, qf[ks], sacc[kn], 0, 0, 0);
            }
        }
        __builtin_amdgcn_s_setprio(0);

        if (kt == qt) {   // diagonal tile: causal mask (k_local > q_local)
            int qloc = w * 16 + lr;
#pragma unroll
            for (int kn = 0; kn < 4; ++kn)
#pragma unroll
                for (int r = 0; r < 4; ++r)
                    if (kn * 16 + lg * 4 + r > qloc) sacc[kn][r] = -1e30f;
        }

        // in-register online softmax (16 in-lane + 2 shfl across lg groups)
        float mx = -1e30f;
#pragma unroll
        for (int kn = 0; kn < 4; ++kn) {
            float a0 = fmaxf(sacc[kn][0], sacc[kn][1]);
            float a1 = fmaxf(sacc[kn][2], sacc[kn][3]);
            mx = fmaxf(mx, fmaxf(a0, a1));
        }
        mx = fmaxf(mx, __shfl_xor(mx, 16));
        mx = fmaxf(mx, __shfl_xor(mx, 32));

        bool noresc = __all(mx <= mrun + 8.0f);   // defer-max: P bounded by 2^(8*SCL)=2.7
        float mnew = noresc ? mrun : fmaxf(mrun, mx);

        float rs = 0.f;
#pragma unroll
        for (int kn = 0; kn < 4; ++kn)
#pragma unroll
            for (int r = 0; r < 4; ++r) {
                float pv = exp2f((sacc[kn][r] - mnew) * SCL);
                sacc[kn][r] = pv;
                rs += pv;
            }
        rs += __shfl_xor(rs, 16);
        rs += __shfl_xor(rs, 32);

        if (noresc) {
            lrun += rs;
        } else {
            float fsc = exp2f((mrun - mnew) * SCL);
            mrun = mnew;
            lrun = lrun * fsc + rs;
            float f0 = __shfl(fsc, lg * 4 + 0);
            float f1 = __shfl(fsc, lg * 4 + 1);
            float f2 = __shfl(fsc, lg * 4 + 2);
            float f3 = __shfl(fsc, lg * 4 + 3);
#pragma unroll
            for (int dc = 0; dc < 4; ++dc) {
                oacc[dc][0] *= f0; oacc[dc][1] *= f1;
                oacc[dc][2] *= f2; oacc[dc][3] *= f3;
            }
        }

        // P -> LDS, packed 8B writes, swizzled (wave-private slab: no barrier needed)
#pragma unroll
        for (int kn = 0; kn < 4; ++kn) {
            bf16x4 pb;
            pb[0] = (__bf16)sacc[kn][0]; pb[1] = (__bf16)sacc[kn][1];
            pb[2] = (__bf16)sacc[kn][2]; pb[3] = (__bf16)sacc[kn][3];
            int byteoff = prow * 128 + (((2 * kn + (lg >> 1)) ^ (prow & 7)) * 16) + (lg & 1) * 8;
            *reinterpret_cast<bf16x4*>(reinterpret_cast<char*>(p_lds) + byteoff) = pb;
        }

        // O += P V  (A = P rows, B = Vt rows); lgkmcnt orders p_lds write->read in-wave
        __builtin_amdgcn_s_setprio(1);
#pragma unroll
        for (int ks = 0; ks < 2; ++ks) {
            bf16x8 pf = *reinterpret_cast<const bf16x8*>(
                reinterpret_cast<char*>(p_lds) + prow * 128 + (((ks * 4 + lg) ^ (prow & 7)) * 16));
#pragma unroll
            for (int dc = 0; dc < 4; ++dc) {
                bf16x8 vf = *reinterpret_cast<const bf16x8*>(
                    &v_lds[cur][(dc * 16 + lr) * 64 + (((ks * 4 + lg) ^ (lr & 7)) * 8)]);
                oacc[dc] = __builtin_amdgcn_mfma_f32_16x16x32_bf16(
                    pf, vf, oacc[dc], 0, 0, 0);
            }
        }
        __builtin_amdgcn_s_setprio(0);
        __syncthreads();   // single barrier/tile: k/v_lds[cur] reads done before reuse
    }

    // epilogue: O /= l ; store bf16 [token][h*64+d]
    float inv = 1.f / lrun;
    float i0 = __shfl(inv, lg * 4 + 0);
    float i1 = __shfl(inv, lg * 4 + 1);
    float i2 = __shfl(inv, lg * 4 + 2);
    float i3 = __shfl(inv, lg * 4 + 3);
    u16* ob = outa + (size_t)b * S_ * NX_;
#pragma unroll
    for (int r = 0; r < 4; ++r) {
        float ir = (r == 0) ? i0 : (r == 1) ? i1 : (r == 2) ? i2 : i3;
        int row = qb + w * 16 + lg * 4 + r;
#pragma unroll
        for (int dc = 0; dc < 4; ++dc)
            ob[(size_t)row * NX_ + h * 64 + dc * 16 + lr] = bfbits(oacc[dc][r] * ir);
    }
}

extern "C" void kernel_launch(void* const* d_in, const int* in_sizes, int n_in,
                              void* d_out, int out_size, void* d_ws, size_t ws_size,
                              hipStream_t stream) {
    const float* x        = (const float*)d_in[0];
    const float* c_attn_w = (const float*)d_in[1];
    const float* c_attn_b = (const float*)d_in[2];
    const float* c_proj_w = (const float*)d_in[3];
    const float* c_proj_b = (const float*)d_in[4];
    float* out = (float*)d_out;

    u16* xb     = (u16*)d_ws;                         // [4096][1024] bf16  (8 MB)
    u16* wqkvT  = xb + (size_t)M_ * NX_;              // [3072][1024] bf16  (6 MB)
    u16* wprojT = wqkvT + (size_t)T3_ * NX_;          // [1024][1024] bf16  (2 MB)
    u16* qkv    = wprojT + (size_t)NX_ * NX_;         // [4096][3072] bf16  (24 MB; V part unused)
    u16* attno  = xb;                                 // reuse xb after GEMM1 (8 MB)
    u16* Vtp    = (u16*)d_out;                        // scratch: Vt 8 MB inside 16 MB out;
                                                      // fully overwritten by GEMM2 at the end

    // 1) x -> bf16
    cvt_bf16_kernel<<<(M_ * NX_) / 1024, 256, 0, stream>>>(x, xb);
    // 2) weights -> transposed bf16
    transpose_cvt_kernel<<<(T3_ / 32) * (NX_ / 32), 256, 0, stream>>>(c_attn_w, wqkvT, NX_, T3_);
    transpose_cvt_kernel<<<(NX_ / 32) * (NX_ / 32), 256, 0, stream>>>(c_proj_w, wprojT, NX_, NX_);
    // 3) qkv = x @ c_attn_w + b (bf16 out); V-part written transposed to Vtp
    gemm_bt_kernel<<<(M_ / BM) * (T3_ / BN), 256, 0, stream>>>(
        xb, wqkvT, c_attn_b, qkv, nullptr, Vtp, 2 * NX_, M_, T3_, NX_);
    // 4) attention (CU-balanced qt mapping, 1024 blocks)
    attn_kernel<<<1024, 256, 0, stream>>>(qkv, Vtp, attno);
    // 5) out = attn @ c_proj_w + b  (f32 out)
    gemm_bt_kernel<<<(M_ / BM) * (NX_ / BN), 256, 0, stream>>>(
        attno, wprojT, c_proj_b, nullptr, out, nullptr, 0, M_, NX_, NX_);
}